// Round 11
// baseline (217.009 us; speedup 1.0000x reference)
//
#include <hip/hip_runtime.h>
#include <hip/hip_bf16.h>

#define B_SZ 4
#define T_SEQ 1024
#define DM 128
#define ED_ 256
#define NS 64
#define LOG2E 1.44269504088896340736f

// workspace layout (float elements). Total = 6,389,760 floats = 25.6 MB (accepted size).
// dxpT is TRANSPOSED [b][e][t] x {delta, delta*xs}; yrT is TRANSPOSED [b][e][t].
// WTi (in_proj transposed) lives in the YR head: k0 -> k24, dead before k5 writes YR.
// WoT (out_proj transposed) lives in the XSR region (now otherwise unused):
// written by k5's extra blocks, read by k6.
#define OFF_Z      0u         /* 524288  f32  z (residual, read by K6)            */
#define OFF_ZG     524288u    /* 1048576 f32  gate (k24 -> k6)                    */
#define OFF_XSR    1572864u   /* region free (no xsr after fusion); head=WoT      */
#define OFF_WC     2621440u   /* 98304   f32  WcT[k][c] transposed combined wt    */
#define OFF_YR     2719744u   /* 1048576 f32  scan out [b][e][t]; head hosts WTi  */
#define OFF_DPX    3768320u   /* 2097152 f32  {delta, delta*xs} [b][e][t] pairs   */
#define OFF_BC     5865472u   /* 524288  f32  {B, C} [b][t][n] pairs (k24 -> k5)  */

__device__ __forceinline__ float sigmoidf_(float x){ return 1.f/(1.f+__expf(-x)); }
__device__ __forceinline__ float exp2_(float x){ return __builtin_amdgcn_exp2f(x); }
__device__ __forceinline__ float rlane_(float v, int l){
  return __int_as_float(__builtin_amdgcn_readlane(__float_as_int(v), l));
}
// collect: accI[lane t] = total of pp (total sits in lane 63 after DPP6).
// v_writelane reads ONE SGPR max -> lane select must be an immediate.
__device__ __forceinline__ void collect_(int &accI, float pp, int t){
  int s;
  asm("v_readlane_b32 %0, %1, 63" : "=s"(s) : "v"(__float_as_int(pp)));
  asm("v_writelane_b32 %0, %1, %2" : "+v"(accI) : "s"(s), "i"(t));
}

// Fused DPP add: p += dpp(p) in ONE instruction. bound_ctrl:0 => invalid lanes read 0.
#define DPPR(p, ctl) asm("v_add_f32_dpp %0, %0, %0 " ctl " row_mask:0xf bank_mask:0xf bound_ctrl:0" : "+v"(p))
#define DPP6(p) do{ DPPR(p,"row_shr:1"); DPPR(p,"row_shr:2"); DPPR(p,"row_shr:4"); \
                    DPPR(p,"row_shr:8"); DPPR(p,"row_bcast:15"); DPPR(p,"row_bcast:31"); }while(0)

// K0: blocks 0..127 transpose in_proj W -> WTi[k][c] (128x512).
//     blocks 128..511 build WcT[k][c] (combined x_proj/dt weight, transposed).
// Both must precede k24 (same-kernel ordering is undefined -> separate kernel).
__global__ __launch_bounds__(256) void k0_prep(const float* W, const float* xprojW, const float* dtW,
                                               float* WTi, float* WcT){
  if (blockIdx.x < 128){
    int k = blockIdx.x;        // 0..127
    int c = threadIdx.x;       // 0..255
    WTi[k*512 + c]       = W[(size_t)c*128 + k];
    WTi[k*512 + c + 256] = W[(size_t)(c+256)*128 + k];
    return;
  }
  int r = blockIdx.x - 128; int k = threadIdx.x;
  float v;
  if (r < 256){
    v = 0.f;
    #pragma unroll
    for (int j=0;j<8;j++) v += dtW[r*8+j] * xprojW[j*256+k];
  } else {
    v = xprojW[(8 + r-256)*256 + k];
  }
  WcT[k*384 + r] = v;
}

// K24: FUSED k2+k4b. Per block: 8 own bt rows (+3 halo rows for conv).
//  stage1: z = zseq+aux@auxW.T+auxb; zn = RMSNorm(z)*rms_w -> at[128][12] for
//          11 rows (h=0..10 => bt0-3..bt0+7). Halo rows: no z write; block 0
//          zeroes invalid rows (conv guards make them unused anyway).
//  stage2: in_proj GEMM, thread=column c0: acc0[11] (xsr col, incl. halo),
//          acc1[8] (zg col). +19% FMA vs unfused, but conv inputs land IN
//          REGISTERS: conv(bt0+r) taps = acc0[r..r+3]. No xsr array at all
//          (kills 9MB HBM round-trip + one kernel launch + one full barrier).
//  stage3: conv+bias+SiLU from acc0 -> xsl[256][12] (48B stride: 16B-aligned
//          b128 reads; gcd-based bank spread on writes).
//  stage4: x_proj pass A (delta cols 0..255, all threads) -> softplus -> dxp.
//  stage5: pass B (B/C cols 256..383, threads 0..127; wave-uniform branch).
__global__ __launch_bounds__(256,4) void k24(const float* zseq, const float* aux, const float* auxW,
                                             const float* auxb, const float* rmsw, const float* WTi,
                                             const float* convW, const float* convb,
                                             const float* WcT, const float* dtb,
                                             float* z, float* zg, float* dxp, float* bcf){
  __shared__ float at[128][12];
  __shared__ float xsl[256][12];
  int bt0 = blockIdx.x*8; int tid = threadIdx.x;
  int t0 = bt0 & (T_SEQ-1);

  // ---- stage 1: z + RMSNorm for rows h=0..10 (bt = bt0-3+h)
  {
    int l = tid & 31;
    #pragma unroll
    for (int pass=0; pass<2; pass++){
      int h = (pass==0) ? (tid>>5) : (8 + (tid>>5));
      bool active = (pass==0) || (tid < 96);
      if (active){
        int bt = bt0 - 3 + h;
        if (bt >= 0){
          float a0 = aux[bt*3+0], a1 = aux[bt*3+1], a2 = aux[bt*3+2];
          float zv[4]; float ssq = 0.f;
          #pragma unroll
          for (int j=0;j<4;j++){
            int d = l + 32*j;
            float v = zseq[bt*DM+d] + a0*auxW[d*3+0] + a1*auxW[d*3+1] + a2*auxW[d*3+2] + auxb[d];
            zv[j] = v; ssq += v*v;
          }
          #pragma unroll
          for (int m=16;m>=1;m>>=1) ssq += __shfl_xor(ssq, m);
          float rinv = rsqrtf(ssq*(1.f/DM) + 1e-5f);
          #pragma unroll
          for (int j=0;j<4;j++){
            int d = l + 32*j;
            if (h >= 3) z[bt*DM+d] = zv[j];
            at[d][h] = zv[j]*rinv*rmsw[d];
          }
        } else {
          #pragma unroll
          for (int j=0;j<4;j++) at[l+32*j][h] = 0.f;
        }
      }
    }
  }
  __syncthreads();

  // ---- stage 2: in_proj GEMM (coalesced WTi reads, broadcast LDS reads)
  float acc0[11], acc1[8];
  #pragma unroll
  for (int h=0;h<11;h++) acc0[h]=0.f;
  #pragma unroll
  for (int r=0;r<8;r++) acc1[r]=0.f;
  int c0 = tid;
  for (int k=0;k<128;k++){
    float w0 = WTi[k*512 + c0];
    float w1 = WTi[k*512 + c0 + 256];
    float a[12];
    *(float4*)&a[0] = *(const float4*)&at[k][0];
    *(float4*)&a[4] = *(const float4*)&at[k][4];
    *(float4*)&a[8] = *(const float4*)&at[k][8];
    #pragma unroll
    for (int h=0;h<11;h++) acc0[h] = fmaf(a[h], w0, acc0[h]);
    #pragma unroll
    for (int r=0;r<8;r++)  acc1[r] = fmaf(a[3+r], w1, acc1[r]);
  }
  #pragma unroll
  for (int r=0;r<8;r++) zg[(bt0+r)*ED_ + c0] = acc1[r];

  // ---- stage 3: conv(k=4)+bias+SiLU entirely in registers
  {
    float4 cw = *(const float4*)(convW + c0*4);
    float cb = convb[c0];
    #pragma unroll
    for (int r=0;r<8;r++){
      int t = t0 + r;                     // t0 uniform, r const -> uniform branches
      float s = fmaf(acc0[r+3], cw.w, cb);
      if (t >= 1) s = fmaf(acc0[r+2], cw.z, s);
      if (t >= 2) s = fmaf(acc0[r+1], cw.y, s);
      if (t >= 3) s = fmaf(acc0[r+0], cw.x, s);
      xsl[c0][r] = s * sigmoidf_(s);
    }
  }
  __syncthreads();

  // ---- stage 4: x_proj pass A (delta cols) + dxp output
  int b4 = bt0 >> 10;
  {
    float acc[8];
    #pragma unroll
    for (int r=0;r<8;r++) acc[r]=0.f;
    int c = tid;
    for (int k=0;k<256;k++){
      float w = WcT[k*384 + c];
      float a[8];
      *(float4*)&a[0] = *(const float4*)&xsl[k][0];
      *(float4*)&a[4] = *(const float4*)&xsl[k][4];
      #pragma unroll
      for (int r=0;r<8;r++) acc[r] = fmaf(a[r], w, acc[r]);
    }
    float bcv = dtb[c];
    float2* pout = (float2*)dxp + (size_t)(b4*ED_ + c)*T_SEQ + t0;
    #pragma unroll
    for (int r=0;r<8;r++){
      float xv = acc[r] + bcv;
      float dv = (xv > 20.f) ? xv : log1pf(__expf(xv));
      pout[r] = make_float2(dv, dv * xsl[c][r]);
    }
  }
  // ---- stage 5: pass B (B/C cols; waves 0-1 only, uniform branch)
  if (tid < 128){
    int c = 256 + tid;
    float acc[8];
    #pragma unroll
    for (int r=0;r<8;r++) acc[r]=0.f;
    for (int k=0;k<256;k++){
      float w = WcT[k*384 + c];
      float a[8];
      *(float4*)&a[0] = *(const float4*)&xsl[k][0];
      *(float4*)&a[4] = *(const float4*)&xsl[k][4];
      #pragma unroll
      for (int r=0;r<8;r++) acc[r] = fmaf(a[r], w, acc[r]);
    }
    if (tid < 64){
      #pragma unroll
      for (int r=0;r<8;r++) bcf[((size_t)(bt0+r)*NS + tid)*2 + 0] = acc[r];
    } else {
      #pragma unroll
      for (int r=0;r<8;r++) bcf[((size_t)(bt0+r)*NS + (tid-64))*2 + 1] = acc[r];
    }
  }
}

// K5: chunked scan — R6 configuration (measured best 63.9us): 4 chunks x 256 t,
// 256-thr block per (b,e), launch_bounds(256,4). Blocks 1024..1055 instead
// transpose out_proj W -> WoT[k][d] into the XSR region for k6.
__global__ __launch_bounds__(256,4) void k5_scan(const float* dxpf, const float* bcf,
                                                  const float* Alog, float* yrT,
                                                  const float* outW, float* wot){
  if (blockIdx.x >= 1024){
    int bb = blockIdx.x - 1024;          // 0..31
    int k  = bb*8 + (threadIdx.x>>5);    // 0..255
    int d  = (threadIdx.x&31)*4;         // 0..124
    float4 v;
    v.x = outW[(d+0)*256 + k];
    v.y = outW[(d+1)*256 + k];
    v.z = outW[(d+2)*256 + k];
    v.w = outW[(d+3)*256 + k];
    *(float4*)&wot[k*128 + d] = v;
    return;
  }
  __shared__ float lcar[3][64], lapr[3][64];
  int i = blockIdx.x;
  int w = threadIdx.x >> 6;      // chunk 0..3
  int n = threadIdx.x & 63;      // state index (lane)
  int x = i & 7;                 // XCD swizzle
  int r = i >> 3;
  int b = r & 3;
  int g = r >> 2;                // 0..31
  int e = x*32 + g;
  const int CH = T_SEQ/4;        // 256
  int t0 = w*CH;
  float A2 = -__expf(Alog[e*NS+n]) * LOG2E;
  const float2* pd  = (const float2*)dxpf + (size_t)(b*ED_ + e)*T_SEQ + t0;  // lane=t
  const float2* pbc = (const float2*)bcf  + (size_t)(b*T_SEQ + t0)*NS + n;   // lane=n
  float*        py  = yrT + (size_t)(b*ED_ + e)*T_SEQ + t0;

  // ---- phase 1: carry-only scan (waves 0..2)
  if (w < 3){
    float h = 0.f, Ssum = 0.f;
    float2 dxc = pd[n];
    for (int sb=0; sb<CH; sb+=64){
      float2 dxn = dxc;
      if (sb+64 < CH) dxn = pd[sb+64+n];
      float sv = dxc.x;
      DPP6(sv);
      Ssum += rlane_(sv, 63);
      float bA[8], bB[8];
      #pragma unroll
      for (int j=0;j<8;j++) bA[j] = pbc[(sb+j)*NS].x;
      #pragma unroll
      for (int bb=0; bb<64; bb+=16){
        #pragma unroll
        for (int j=0;j<8;j++) bB[j] = pbc[(sb+bb+8+j)*NS].x;
        #pragma unroll
        for (int j=0;j<8;j++){
          float sd = rlane_(dxc.x, bb+j);
          float su = rlane_(dxc.y, bb+j);
          h = fmaf(exp2_(sd*A2), h, su*bA[j]);
        }
        if (bb+16 < 64){
          #pragma unroll
          for (int j=0;j<8;j++) bA[j] = pbc[(sb+bb+16+j)*NS].x;
        }
        #pragma unroll
        for (int j=0;j<8;j++){
          float sd = rlane_(dxc.x, bb+8+j);
          float su = rlane_(dxc.y, bb+8+j);
          h = fmaf(exp2_(sd*A2), h, su*bB[j]);
        }
      }
      dxc = dxn;
    }
    lcar[w][n] = h;
    lapr[w][n] = exp2_(A2*Ssum);
  }
  __syncthreads();

  // ---- combine: h_in for this wave's chunk
  float h = 0.f;
  if (w >= 1) h = lcar[0][n];
  if (w >= 2) h = fmaf(lapr[1][n], h, lcar[1][n]);
  if (w >= 3) h = fmaf(lapr[2][n], h, lcar[2][n]);

  // ---- phase 2: full output scan
  {
    float2 dxc = pd[n];
    for (int sb=0; sb<CH; sb+=64){
      float2 dxn = dxc;
      if (sb+64 < CH) dxn = pd[sb+64+n];
      int accI = 0;
      float2 cA[8], cB[8];
      #pragma unroll
      for (int j=0;j<8;j++) cA[j] = pbc[(sb+j)*NS];
      #pragma unroll
      for (int bb=0; bb<64; bb+=16){
        #pragma unroll
        for (int j=0;j<8;j++) cB[j] = pbc[(sb+bb+8+j)*NS];
        #pragma unroll
        for (int j=0;j<8;j++){
          float sd = rlane_(dxc.x, bb+j);
          float su = rlane_(dxc.y, bb+j);
          h = fmaf(exp2_(sd*A2), h, su*cA[j].x);
          float pp = h*cA[j].y;
          DPP6(pp);
          collect_(accI, pp, bb+j);
        }
        if (bb+16 < 64){
          #pragma unroll
          for (int j=0;j<8;j++) cA[j] = pbc[(sb+bb+16+j)*NS];
        }
        #pragma unroll
        for (int j=0;j<8;j++){
          float sd = rlane_(dxc.x, bb+8+j);
          float su = rlane_(dxc.y, bb+8+j);
          h = fmaf(exp2_(sd*A2), h, su*cB[j].x);
          float pp = h*cB[j].y;
          DPP6(pp);
          collect_(accI, pp, bb+8+j);
        }
      }
      py[sb+n] = __int_as_float(accI);
      dxc = dxn;
    }
  }
}

// K6: stage yrT (e-major) + xs = u/delta from dxpT via LDS; combine with gate;
// then out = LayerNorm(y @ out_proj_W.T + 2*z)*ln_w + ln_b. WoT reads coalesced.
__global__ __launch_bounds__(256) void k6_out(const float* yrT, const float* dxpf, const float* zg,
                                               const float* Dp, const float* wot, const float* z,
                                               const float* lnw, const float* lnb, float* out){
  __shared__ float yt[256][8];
  __shared__ float xst[256][8];
  __shared__ float psum[4][4], psq[4][4];
  int bt0 = blockIdx.x*8; int tid = threadIdx.x;
  int b4 = bt0 >> 10, tb = bt0 & (T_SEQ-1);
  int el = tid>>3, tl = tid&7;
  #pragma unroll
  for (int gg=0; gg<8; gg++){
    int ee = el + gg*32;
    size_t base = (size_t)(b4*ED_ + ee)*T_SEQ + tb + tl;
    float2 du = ((const float2*)dxpf)[base];
    yt[ee][tl]  = yrT[base];
    xst[ee][tl] = du.y / du.x;        // xs = (delta*xs)/delta; delta >= softplus(-4) ~ 0.018
  }
  __syncthreads();
  for (int i=tid;i<2048;i+=256){
    int rr=i>>8, k=i&255; int bt=bt0+rr;
    float zgv = zg[bt*ED_ + k];
    float yv  = yt[k][rr] + Dp[k]*xst[k][rr];
    yt[k][rr] = yv * zgv * sigmoidf_(zgv);
  }
  __syncthreads();
  int d = tid & 127, gdx = tid>>7;
  float acc[4] = {0.f,0.f,0.f,0.f};
  for (int k=0;k<256;k+=4){
    float w0 = wot[(k+0)*128 + d];       // coalesced
    float w1 = wot[(k+1)*128 + d];
    float w2 = wot[(k+2)*128 + d];
    float w3 = wot[(k+3)*128 + d];
    float4 q0 = *(const float4*)&yt[k+0][gdx*4];   // broadcast
    float4 q1 = *(const float4*)&yt[k+1][gdx*4];
    float4 q2 = *(const float4*)&yt[k+2][gdx*4];
    float4 q3 = *(const float4*)&yt[k+3][gdx*4];
    acc[0] = fmaf(q0.x,w0,acc[0]); acc[1] = fmaf(q0.y,w0,acc[1]);
    acc[2] = fmaf(q0.z,w0,acc[2]); acc[3] = fmaf(q0.w,w0,acc[3]);
    acc[0] = fmaf(q1.x,w1,acc[0]); acc[1] = fmaf(q1.y,w1,acc[1]);
    acc[2] = fmaf(q1.z,w1,acc[2]); acc[3] = fmaf(q1.w,w1,acc[3]);
    acc[0] = fmaf(q2.x,w2,acc[0]); acc[1] = fmaf(q2.y,w2,acc[1]);
    acc[2] = fmaf(q2.z,w2,acc[2]); acc[3] = fmaf(q2.w,w2,acc[3]);
    acc[0] = fmaf(q3.x,w3,acc[0]); acc[1] = fmaf(q3.y,w3,acc[1]);
    acc[2] = fmaf(q3.z,w3,acc[2]); acc[3] = fmaf(q3.w,w3,acc[3]);
  }
  float val[4];
  #pragma unroll
  for (int j=0;j<4;j++){
    int bt = bt0 + gdx*4 + j;
    val[j] = acc[j] + 2.f*z[bt*DM + d];
  }
  int w_id = tid>>6;
  #pragma unroll
  for (int j=0;j<4;j++){
    float s = val[j], q = val[j]*val[j];
    #pragma unroll
    for (int off=32; off>=1; off>>=1){ s += __shfl_down(s, off); q += __shfl_down(q, off); }
    if ((tid&63)==0){ psum[w_id][j]=s; psq[w_id][j]=q; }
  }
  __syncthreads();
  float lw = lnw[d], lb = lnb[d];
  #pragma unroll
  for (int j=0;j<4;j++){
    int bt = bt0 + gdx*4 + j;
    float sum = psum[gdx*2][j] + psum[gdx*2+1][j];
    float sq  = psq [gdx*2][j] + psq [gdx*2+1][j];
    float mu  = sum*(1.f/DM);
    float var = sq*(1.f/DM) - mu*mu;
    float inv = rsqrtf(var + 1e-5f);
    out[bt*DM + d] = (val[j]-mu)*inv*lw + lb;
  }
}

extern "C" void kernel_launch(void* const* d_in, const int* in_sizes, int n_in,
                              void* d_out, int out_size, void* d_ws, size_t ws_size,
                              hipStream_t stream){
  const float* zseq = (const float*)d_in[0];
  const float* aux  = (const float*)d_in[1];
  const float* auxW = (const float*)d_in[2];
  const float* auxb = (const float*)d_in[3];
  const float* lnw  = (const float*)d_in[4];
  const float* lnb  = (const float*)d_in[5];
  const float* rmsw = (const float*)d_in[6];
  const float* inW  = (const float*)d_in[7];
  const float* convW= (const float*)d_in[8];
  const float* convb= (const float*)d_in[9];
  const float* xpW  = (const float*)d_in[10];
  const float* dtW  = (const float*)d_in[11];
  const float* dtb  = (const float*)d_in[12];
  const float* Alog = (const float*)d_in[13];
  const float* Dp   = (const float*)d_in[14];
  const float* outW = (const float*)d_in[15];
  float* out = (float*)d_out;
  float* ws = (float*)d_ws;

  float* z   = ws+OFF_Z;
  float* zg  = ws+OFF_ZG;
  float* wot = ws+OFF_XSR;   // WoT hosted in (now free) XSR region
  float* WcT = ws+OFF_WC;
  float* yr  = ws+OFF_YR;
  float* wti = ws+OFF_YR;    // WTi hosted in YR head; dead before k5 writes yr
  float* dxp = ws+OFF_DPX;
  float* bcp = ws+OFF_BC;

  k0_prep <<<512,256,0,stream>>>(inW, xpW, dtW, wti, WcT);
  k24     <<<512,256,0,stream>>>(zseq,aux,auxW,auxb,rmsw,wti,convW,convb,WcT,dtb,z,zg,dxp,bcp);
  k5_scan <<<1056,256,0,stream>>>(dxp,bcp,Alog,yr,outW,wot);
  k6_out  <<<512,256,0,stream>>>(yr,dxp,zg,Dp,wot,z,lnw,lnb,out);
}

// Round 12
// 202.070 us; speedup vs baseline: 1.0739x; 1.0739x over previous
//
#include <hip/hip_runtime.h>
#include <hip/hip_bf16.h>

#define B_SZ 4
#define T_SEQ 1024
#define DM 128
#define ED_ 256
#define NS 64
#define LOG2E 1.44269504088896340736f

// workspace layout (float elements). Total = 6,389,760 floats = 25.6 MB (accepted size).
// dxpT is TRANSPOSED [b][e][t] x {delta, delta*xs}; yrT is TRANSPOSED [b][e][t].
// WTi (in_proj transposed) lives in the YR head: k0 -> k2, dead before k5 writes YR.
// WoT (out_proj transposed) lives in the XSR head: written by k5's extra blocks, read by k6.
#define OFF_Z      0u         /* 524288  f32  z (residual, read by K6)            */
#define OFF_ZG     524288u    /* 1048576 f32  gate (k2 -> k6)                     */
#define OFF_XSR    1572864u   /* 1048576 f32  conv input (k2 -> k4b); head=WoT    */
#define OFF_WC     2621440u   /* 98304   f32  WcT[k][c] transposed combined wt    */
#define OFF_YR     2719744u   /* 1048576 f32  scan out [b][e][t]; head hosts WTi  */
#define OFF_DPX    3768320u   /* 2097152 f32  {delta, delta*xs} [b][e][t] pairs   */
#define OFF_BC     5865472u   /* 524288  f32  {B, C} [b][t][n] pairs (k4b -> k5)  */

__device__ __forceinline__ float sigmoidf_(float x){ return 1.f/(1.f+__expf(-x)); }
__device__ __forceinline__ float exp2_(float x){ return __builtin_amdgcn_exp2f(x); }
__device__ __forceinline__ float rlane_(float v, int l){
  return __int_as_float(__builtin_amdgcn_readlane(__float_as_int(v), l));
}

// Fused DPP add: p += dpp(p) in ONE instruction. bound_ctrl:0 => invalid lanes read 0.
#define DPPR(p, ctl) asm("v_add_f32_dpp %0, %0, %0 " ctl " row_mask:0xf bank_mask:0xf bound_ctrl:0" : "+v"(p))
#define DPP6(p) do{ DPPR(p,"row_shr:1"); DPPR(p,"row_shr:2"); DPPR(p,"row_shr:4"); \
                    DPPR(p,"row_shr:8"); DPPR(p,"row_bcast:15"); DPPR(p,"row_bcast:31"); }while(0)

// K0: transpose in_proj W (512x128 row-major) -> WTi[k][c] (128x512).
__global__ __launch_bounds__(256) void k0_t(const float* W, float* WTi){
  int k = blockIdx.x;        // 0..127
  int c = threadIdx.x;       // 0..255
  WTi[k*512 + c]       = W[(size_t)c*128 + k];
  WTi[k*512 + c + 256] = W[(size_t)(c+256)*128 + k];
}

// K2f: blocks 0..511: fused [z = zseq+aux@auxW.T+auxb ; zn=RMSNorm(z)*rms_w] -> LDS,
//      then xz = zn @ in_proj_W.T -> xsr | zg, reading WTi[k][c] COALESCED.
//      blocks 512..895: build WcT[k][c] (transposed combined x_proj/dt weight).
__global__ __launch_bounds__(256) void k2_fused(const float* zseq, const float* aux, const float* auxW,
                                                const float* auxb, const float* rmsw, const float* WTi,
                                                const float* xprojW, const float* dtW,
                                                float* z, float* xsr, float* zg, float* WcT){
  if (blockIdx.x >= 512){
    int r = blockIdx.x - 512; int k = threadIdx.x;
    float v;
    if (r < 256){
      v = 0.f;
      #pragma unroll
      for (int j=0;j<8;j++) v += dtW[r*8+j] * xprojW[j*256+k];
    } else {
      v = xprojW[(8 + r-256)*256 + k];
    }
    WcT[k*384 + r] = v;      // transposed store (uncoalesced but one-off)
    return;
  }
  __shared__ float at[128][8];
  int bt0 = blockIdx.x*8; int tid = threadIdx.x;
  {
    int r = tid>>5, l = tid&31;
    int bt = bt0 + r;
    float a0 = aux[bt*3+0], a1 = aux[bt*3+1], a2 = aux[bt*3+2];
    float zv[4]; float ssq = 0.f;
    #pragma unroll
    for (int j=0;j<4;j++){
      int d = l + 32*j;
      float v = zseq[bt*DM+d] + a0*auxW[d*3+0] + a1*auxW[d*3+1] + a2*auxW[d*3+2] + auxb[d];
      zv[j] = v; ssq += v*v;
    }
    #pragma unroll
    for (int m=16;m>=1;m>>=1) ssq += __shfl_xor(ssq, m);
    float rinv = rsqrtf(ssq*(1.f/DM) + 1e-5f);
    #pragma unroll
    for (int j=0;j<4;j++){
      int d = l + 32*j;
      z[bt*DM+d] = zv[j];
      at[d][r] = zv[j]*rinv*rmsw[d];
    }
  }
  __syncthreads();
  float acc0[8], acc1[8];
  #pragma unroll
  for (int r=0;r<8;r++){ acc0[r]=0.f; acc1[r]=0.f; }
  int c0 = tid;
  for (int k=0;k<128;k++){
    float w0 = WTi[k*512 + c0];          // coalesced: lanes -> consecutive floats
    float w1 = WTi[k*512 + c0 + 256];
    float a[8];
    *(float4*)&a[0] = *(const float4*)&at[k][0];   // broadcast b128 (conflict-free)
    *(float4*)&a[4] = *(const float4*)&at[k][4];
    #pragma unroll
    for (int r=0;r<8;r++){ acc0[r] = fmaf(a[r], w0, acc0[r]); acc1[r] = fmaf(a[r], w1, acc1[r]); }
  }
  #pragma unroll
  for (int r=0;r<8;r++){
    int bt = bt0+r;
    xsr[bt*ED_ + c0] = acc0[r];
    zg [bt*ED_ + c0] = acc1[r];
  }
}

// K4b: conv(k=4)+bias+SiLU from xsr (LDS), then [delta_pre | B | C] = xs @ WcT.
// Weight reads COALESCED (WcT[k][c], c=tid).
__global__ __launch_bounds__(384) void k4b_xproj(const float* xsr, const float* convW, const float* convb,
                                                 const float* WcT, const float* dtb,
                                                 float* dxp, float* bcf){
  __shared__ float at[256][8];
  int bt0 = blockIdx.x*8; int tid = threadIdx.x;
  for (int i=tid;i<2048;i+=384){
    int r=i>>8,k=i&255; int bt=bt0+r; int t = bt & (T_SEQ-1);
    float4 wv = *(const float4*)(convW + k*4);
    float s = convb[k];
    if (t>=3) s += xsr[(bt-3)*ED_+k]*wv.x;
    if (t>=2) s += xsr[(bt-2)*ED_+k]*wv.y;
    if (t>=1) s += xsr[(bt-1)*ED_+k]*wv.z;
    s += xsr[bt*ED_+k]*wv.w;
    at[k][r] = s * sigmoidf_(s);
  }
  __syncthreads();
  float acc[8];
  #pragma unroll
  for (int r=0;r<8;r++) acc[r]=0.f;
  int c = tid;
  for (int k=0;k<256;k++){
    float w = WcT[k*384 + c];            // coalesced
    float a[8];
    *(float4*)&a[0] = *(const float4*)&at[k][0];   // broadcast
    *(float4*)&a[4] = *(const float4*)&at[k][4];
    #pragma unroll
    for (int r=0;r<8;r++) acc[r] = fmaf(a[r], w, acc[r]);
  }
  int b4 = bt0 >> 10, tb = bt0 & (T_SEQ-1);
  if (c < 256){
    float bcv = dtb[c];
    float2* pout = (float2*)dxp + (size_t)(b4*ED_ + c)*T_SEQ + tb;
    #pragma unroll
    for (int r=0;r<8;r++){
      float xv = acc[r] + bcv;
      float dv = (xv > 20.f) ? xv : log1pf(__expf(xv));
      pout[r] = make_float2(dv, dv * at[c][r]);   // {delta, delta*xs}
    }
  } else if (c < 320){
    #pragma unroll
    for (int r=0;r<8;r++) bcf[((size_t)(bt0+r)*NS + (c-256))*2 + 0] = acc[r];
  } else {
    #pragma unroll
    for (int r=0;r<8;r++) bcf[((size_t)(bt0+r)*NS + (c-320))*2 + 1] = acc[r];
  }
}

// K5: chunked scan. R10 structure (4 chunks x 256 t, 256-thr block per (b,e),
// launch_bounds(256,4); blocks 1024..1055 transpose out_proj -> WoT).
// NEW: phase-2 per-t DPP6+readlane/writelane (8 instr/t) replaced by LDS
// transpose-reduce: write pp to red[w][t&15][n] (1 ds_write/t, 2-way banks =
// free), every 16 t transpose-read (8 ds_read_b64/lane, stride-66 pad),
// 15 adds + 2 shfl_xor, coalesced 64B store from lanes 0..15. Same-wave DS
// ops are in-order -> no barrier. ~2.9 instr/t amortized vs 8.
__global__ __launch_bounds__(256,4) void k5_scan(const float* dxpf, const float* bcf,
                                                  const float* Alog, float* yrT,
                                                  const float* outW, float* wot){
  if (blockIdx.x >= 1024){
    int bb = blockIdx.x - 1024;          // 0..31
    int k  = bb*8 + (threadIdx.x>>5);    // 0..255
    int d  = (threadIdx.x&31)*4;         // 0..124
    float4 v;
    v.x = outW[(d+0)*256 + k];
    v.y = outW[(d+1)*256 + k];
    v.z = outW[(d+2)*256 + k];
    v.w = outW[(d+3)*256 + k];
    *(float4*)&wot[k*128 + d] = v;
    return;
  }
  __shared__ float lcar[3][64], lapr[3][64];
  __shared__ float red[4][16][66];       // per-wave transpose-reduce tile (stride 66: 8B-aligned, 2-way banks)
  int i = blockIdx.x;
  int w = threadIdx.x >> 6;      // chunk 0..3
  int n = threadIdx.x & 63;      // state index (lane)
  int x = i & 7;                 // XCD swizzle
  int r = i >> 3;
  int b = r & 3;
  int g = r >> 2;                // 0..31
  int e = x*32 + g;
  const int CH = T_SEQ/4;        // 256
  int t0 = w*CH;
  float A2 = -__expf(Alog[e*NS+n]) * LOG2E;
  const float2* pd  = (const float2*)dxpf + (size_t)(b*ED_ + e)*T_SEQ + t0;  // lane=t
  const float2* pbc = (const float2*)bcf  + (size_t)(b*T_SEQ + t0)*NS + n;   // lane=n
  float*        py  = yrT + (size_t)(b*ED_ + e)*T_SEQ + t0;

  // ---- phase 1: carry-only scan (waves 0..2)
  if (w < 3){
    float h = 0.f, Ssum = 0.f;
    float2 dxc = pd[n];
    for (int sb=0; sb<CH; sb+=64){
      float2 dxn = dxc;
      if (sb+64 < CH) dxn = pd[sb+64+n];
      float sv = dxc.x;
      DPP6(sv);
      Ssum += rlane_(sv, 63);
      float bA[8], bB[8];
      #pragma unroll
      for (int j=0;j<8;j++) bA[j] = pbc[(sb+j)*NS].x;
      #pragma unroll
      for (int bb=0; bb<64; bb+=16){
        #pragma unroll
        for (int j=0;j<8;j++) bB[j] = pbc[(sb+bb+8+j)*NS].x;
        #pragma unroll
        for (int j=0;j<8;j++){
          float sd = rlane_(dxc.x, bb+j);
          float su = rlane_(dxc.y, bb+j);
          h = fmaf(exp2_(sd*A2), h, su*bA[j]);
        }
        if (bb+16 < 64){
          #pragma unroll
          for (int j=0;j<8;j++) bA[j] = pbc[(sb+bb+16+j)*NS].x;
        }
        #pragma unroll
        for (int j=0;j<8;j++){
          float sd = rlane_(dxc.x, bb+8+j);
          float su = rlane_(dxc.y, bb+8+j);
          h = fmaf(exp2_(sd*A2), h, su*bB[j]);
        }
      }
      dxc = dxn;
    }
    lcar[w][n] = h;
    lapr[w][n] = exp2_(A2*Ssum);
  }
  __syncthreads();

  // ---- combine: h_in for this wave's chunk
  float h = 0.f;
  if (w >= 1) h = lcar[0][n];
  if (w >= 2) h = fmaf(lapr[1][n], h, lcar[1][n]);
  if (w >= 3) h = fmaf(lapr[2][n], h, lcar[2][n]);

  // ---- phase 2: full output scan with LDS transpose-reduce
  {
    float2 dxc = pd[n];
    int lr = n & 15;             // row this lane sums in the read phase
    int lq = n >> 4;             // quarter of that row
    const float2* rp = (const float2*)&red[w][lr][lq*16];
    for (int sb=0; sb<CH; sb+=64){
      float2 dxn = dxc;
      if (sb+64 < CH) dxn = pd[sb+64+n];
      float2 cA[8], cB[8];
      #pragma unroll
      for (int j=0;j<8;j++) cA[j] = pbc[(sb+j)*NS];
      #pragma unroll
      for (int bb=0; bb<64; bb+=16){
        #pragma unroll
        for (int j=0;j<8;j++) cB[j] = pbc[(sb+bb+8+j)*NS];
        #pragma unroll
        for (int j=0;j<8;j++){
          float sd = rlane_(dxc.x, bb+j);
          float su = rlane_(dxc.y, bb+j);
          h = fmaf(exp2_(sd*A2), h, su*cA[j].x);
          red[w][j][n] = h*cA[j].y;
        }
        if (bb+16 < 64){
          #pragma unroll
          for (int j=0;j<8;j++) cA[j] = pbc[(sb+bb+16+j)*NS];
        }
        #pragma unroll
        for (int j=0;j<8;j++){
          float sd = rlane_(dxc.x, bb+8+j);
          float su = rlane_(dxc.y, bb+8+j);
          h = fmaf(exp2_(sd*A2), h, su*cB[j].x);
          red[w][8+j][n] = h*cB[j].y;
        }
        // transpose-reduce the 16-row tile (same-wave DS ops are in-order)
        float2 v0 = rp[0], v1 = rp[1], v2 = rp[2], v3 = rp[3];
        float2 v4 = rp[4], v5 = rp[5], v6 = rp[6], v7 = rp[7];
        float s0 = ((v0.x+v0.y)+(v1.x+v1.y)) + ((v2.x+v2.y)+(v3.x+v3.y))
                 + ((v4.x+v4.y)+(v5.x+v5.y)) + ((v6.x+v6.y)+(v7.x+v7.y));
        s0 += __shfl_xor(s0, 32);
        s0 += __shfl_xor(s0, 16);
        if (n < 16) py[sb + bb + n] = s0;
      }
      dxc = dxn;
    }
  }
}

// K6: stage yrT (e-major) + xs = u/delta from dxpT via LDS; combine with gate;
// then out = LayerNorm(y @ out_proj_W.T + 2*z)*ln_w + ln_b. WoT reads coalesced.
__global__ __launch_bounds__(256) void k6_out(const float* yrT, const float* dxpf, const float* zg,
                                               const float* Dp, const float* wot, const float* z,
                                               const float* lnw, const float* lnb, float* out){
  __shared__ float yt[256][8];
  __shared__ float xst[256][8];
  __shared__ float psum[4][4], psq[4][4];
  int bt0 = blockIdx.x*8; int tid = threadIdx.x;
  int b4 = bt0 >> 10, tb = bt0 & (T_SEQ-1);
  int el = tid>>3, tl = tid&7;
  #pragma unroll
  for (int gg=0; gg<8; gg++){
    int ee = el + gg*32;
    size_t base = (size_t)(b4*ED_ + ee)*T_SEQ + tb + tl;
    float2 du = ((const float2*)dxpf)[base];
    yt[ee][tl]  = yrT[base];
    xst[ee][tl] = du.y / du.x;        // xs = (delta*xs)/delta; delta >= softplus(-4) ~ 0.018
  }
  __syncthreads();
  for (int i=tid;i<2048;i+=256){
    int rr=i>>8, k=i&255; int bt=bt0+rr;
    float zgv = zg[bt*ED_ + k];
    float yv  = yt[k][rr] + Dp[k]*xst[k][rr];
    yt[k][rr] = yv * zgv * sigmoidf_(zgv);
  }
  __syncthreads();
  int d = tid & 127, gdx = tid>>7;
  float acc[4] = {0.f,0.f,0.f,0.f};
  for (int k=0;k<256;k+=4){
    float w0 = wot[(k+0)*128 + d];       // coalesced
    float w1 = wot[(k+1)*128 + d];
    float w2 = wot[(k+2)*128 + d];
    float w3 = wot[(k+3)*128 + d];
    float4 q0 = *(const float4*)&yt[k+0][gdx*4];   // broadcast
    float4 q1 = *(const float4*)&yt[k+1][gdx*4];
    float4 q2 = *(const float4*)&yt[k+2][gdx*4];
    float4 q3 = *(const float4*)&yt[k+3][gdx*4];
    acc[0] = fmaf(q0.x,w0,acc[0]); acc[1] = fmaf(q0.y,w0,acc[1]);
    acc[2] = fmaf(q0.z,w0,acc[2]); acc[3] = fmaf(q0.w,w0,acc[3]);
    acc[0] = fmaf(q1.x,w1,acc[0]); acc[1] = fmaf(q1.y,w1,acc[1]);
    acc[2] = fmaf(q1.z,w1,acc[2]); acc[3] = fmaf(q1.w,w1,acc[3]);
    acc[0] = fmaf(q2.x,w2,acc[0]); acc[1] = fmaf(q2.y,w2,acc[1]);
    acc[2] = fmaf(q2.z,w2,acc[2]); acc[3] = fmaf(q2.w,w2,acc[3]);
    acc[0] = fmaf(q3.x,w3,acc[0]); acc[1] = fmaf(q3.y,w3,acc[1]);
    acc[2] = fmaf(q3.z,w3,acc[2]); acc[3] = fmaf(q3.w,w3,acc[3]);
  }
  float val[4];
  #pragma unroll
  for (int j=0;j<4;j++){
    int bt = bt0 + gdx*4 + j;
    val[j] = acc[j] + 2.f*z[bt*DM + d];
  }
  int w_id = tid>>6;
  #pragma unroll
  for (int j=0;j<4;j++){
    float s = val[j], q = val[j]*val[j];
    #pragma unroll
    for (int off=32; off>=1; off>>=1){ s += __shfl_down(s, off); q += __shfl_down(q, off); }
    if ((tid&63)==0){ psum[w_id][j]=s; psq[w_id][j]=q; }
  }
  __syncthreads();
  float lw = lnw[d], lb = lnb[d];
  #pragma unroll
  for (int j=0;j<4;j++){
    int bt = bt0 + gdx*4 + j;
    float sum = psum[gdx*2][j] + psum[gdx*2+1][j];
    float sq  = psq [gdx*2][j] + psq [gdx*2+1][j];
    float mu  = sum*(1.f/DM);
    float var = sq*(1.f/DM) - mu*mu;
    float inv = rsqrtf(var + 1e-5f);
    out[bt*DM + d] = (val[j]-mu)*inv*lw + lb;
  }
}

extern "C" void kernel_launch(void* const* d_in, const int* in_sizes, int n_in,
                              void* d_out, int out_size, void* d_ws, size_t ws_size,
                              hipStream_t stream){
  const float* zseq = (const float*)d_in[0];
  const float* aux  = (const float*)d_in[1];
  const float* auxW = (const float*)d_in[2];
  const float* auxb = (const float*)d_in[3];
  const float* lnw  = (const float*)d_in[4];
  const float* lnb  = (const float*)d_in[5];
  const float* rmsw = (const float*)d_in[6];
  const float* inW  = (const float*)d_in[7];
  const float* convW= (const float*)d_in[8];
  const float* convb= (const float*)d_in[9];
  const float* xpW  = (const float*)d_in[10];
  const float* dtW  = (const float*)d_in[11];
  const float* dtb  = (const float*)d_in[12];
  const float* Alog = (const float*)d_in[13];
  const float* Dp   = (const float*)d_in[14];
  const float* outW = (const float*)d_in[15];
  float* out = (float*)d_out;
  float* ws = (float*)d_ws;

  float* z   = ws+OFF_Z;
  float* zg  = ws+OFF_ZG;
  float* xsr = ws+OFF_XSR;
  float* wot = ws+OFF_XSR;   // WoT hosted in XSR head; xsr dead after k4b
  float* WcT = ws+OFF_WC;
  float* yr  = ws+OFF_YR;
  float* wti = ws+OFF_YR;    // WTi hosted in YR head; dead before k5 writes yr
  float* dxp = ws+OFF_DPX;
  float* bcp = ws+OFF_BC;

  k0_t     <<<128,256,0,stream>>>(inW, wti);
  k2_fused <<<896,256,0,stream>>>(zseq,aux,auxW,auxb,rmsw,wti,xpW,dtW,z,xsr,zg,WcT);
  k4b_xproj<<<512,384,0,stream>>>(xsr,convW,convb,WcT,dtb,dxp,bcp);
  k5_scan  <<<1056,256,0,stream>>>(dxp,bcp,Alog,yr,outW,wot);
  k6_out   <<<512,256,0,stream>>>(yr,dxp,zg,Dp,wot,z,lnw,lnb,out);
}

// Round 13
// 187.170 us; speedup vs baseline: 1.1594x; 1.0796x over previous
//
#include <hip/hip_runtime.h>
#include <hip/hip_bf16.h>

#define B_SZ 4
#define T_SEQ 1024
#define DM 128
#define ED_ 256
#define NS 64
#define LOG2E 1.44269504088896340736f

// workspace layout (float elements). Total = 6,389,760 floats = 25.6 MB (accepted size).
// dxpT is TRANSPOSED [b][e][t] x {delta, delta*xs}; yrT is TRANSPOSED [b][e][t].
// WTi (in_proj transposed) lives in the YR head: k0 -> k2, dead before k5 writes YR.
// WoT (out_proj transposed) lives in the XSR head: written by k5's extra blocks, read by k6.
#define OFF_Z      0u         /* 524288  f32  z (residual, read by K6)            */
#define OFF_ZG     524288u    /* 1048576 f32  gate (k2 -> k6)                     */
#define OFF_XSR    1572864u   /* 1048576 f32  conv input (k2 -> k4b); head=WoT    */
#define OFF_WC     2621440u   /* 98304   f32  WcT[k][c] transposed combined wt    */
#define OFF_YR     2719744u   /* 1048576 f32  scan out [b][e][t]; head hosts WTi  */
#define OFF_DPX    3768320u   /* 2097152 f32  {delta, delta*xs} [b][e][t] pairs   */
#define OFF_BC     5865472u   /* 524288  f32  {B, C} [b][t][n] pairs (k4b -> k5)  */

__device__ __forceinline__ float sigmoidf_(float x){ return 1.f/(1.f+__expf(-x)); }
__device__ __forceinline__ float exp2_(float x){ return __builtin_amdgcn_exp2f(x); }
__device__ __forceinline__ float rlane_(float v, int l){
  return __int_as_float(__builtin_amdgcn_readlane(__float_as_int(v), l));
}

// Fused DPP add: p += dpp(p) in ONE instruction. bound_ctrl:0 => invalid lanes read 0.
#define DPPR(p, ctl) asm("v_add_f32_dpp %0, %0, %0 " ctl " row_mask:0xf bank_mask:0xf bound_ctrl:0" : "+v"(p))
#define DPP6(p) do{ DPPR(p,"row_shr:1"); DPPR(p,"row_shr:2"); DPPR(p,"row_shr:4"); \
                    DPPR(p,"row_shr:8"); DPPR(p,"row_bcast:15"); DPPR(p,"row_bcast:31"); }while(0)

// K0: transpose in_proj W (512x128 row-major) -> WTi[k][c] (128x512).
__global__ __launch_bounds__(256) void k0_t(const float* W, float* WTi){
  int k = blockIdx.x;        // 0..127
  int c = threadIdx.x;       // 0..255
  WTi[k*512 + c]       = W[(size_t)c*128 + k];
  WTi[k*512 + c + 256] = W[(size_t)(c+256)*128 + k];
}

// K2f: blocks 0..511: fused [z = zseq+aux@auxW.T+auxb ; zn=RMSNorm(z)*rms_w] -> LDS,
//      then xz = zn @ in_proj_W.T -> xsr | zg, reading WTi[k][c] COALESCED.
//      blocks 512..895: build WcT[k][c] (transposed combined x_proj/dt weight).
__global__ __launch_bounds__(256) void k2_fused(const float* zseq, const float* aux, const float* auxW,
                                                const float* auxb, const float* rmsw, const float* WTi,
                                                const float* xprojW, const float* dtW,
                                                float* z, float* xsr, float* zg, float* WcT){
  if (blockIdx.x >= 512){
    int r = blockIdx.x - 512; int k = threadIdx.x;
    float v;
    if (r < 256){
      v = 0.f;
      #pragma unroll
      for (int j=0;j<8;j++) v += dtW[r*8+j] * xprojW[j*256+k];
    } else {
      v = xprojW[(8 + r-256)*256 + k];
    }
    WcT[k*384 + r] = v;      // transposed store (uncoalesced but one-off)
    return;
  }
  __shared__ float at[128][8];
  int bt0 = blockIdx.x*8; int tid = threadIdx.x;
  {
    int r = tid>>5, l = tid&31;
    int bt = bt0 + r;
    float a0 = aux[bt*3+0], a1 = aux[bt*3+1], a2 = aux[bt*3+2];
    float zv[4]; float ssq = 0.f;
    #pragma unroll
    for (int j=0;j<4;j++){
      int d = l + 32*j;
      float v = zseq[bt*DM+d] + a0*auxW[d*3+0] + a1*auxW[d*3+1] + a2*auxW[d*3+2] + auxb[d];
      zv[j] = v; ssq += v*v;
    }
    #pragma unroll
    for (int m=16;m>=1;m>>=1) ssq += __shfl_xor(ssq, m);
    float rinv = rsqrtf(ssq*(1.f/DM) + 1e-5f);
    #pragma unroll
    for (int j=0;j<4;j++){
      int d = l + 32*j;
      z[bt*DM+d] = zv[j];
      at[d][r] = zv[j]*rinv*rmsw[d];
    }
  }
  __syncthreads();
  float acc0[8], acc1[8];
  #pragma unroll
  for (int r=0;r<8;r++){ acc0[r]=0.f; acc1[r]=0.f; }
  int c0 = tid;
  for (int k=0;k<128;k++){
    float w0 = WTi[k*512 + c0];          // coalesced: lanes -> consecutive floats
    float w1 = WTi[k*512 + c0 + 256];
    float a[8];
    *(float4*)&a[0] = *(const float4*)&at[k][0];   // broadcast b128 (conflict-free)
    *(float4*)&a[4] = *(const float4*)&at[k][4];
    #pragma unroll
    for (int r=0;r<8;r++){ acc0[r] = fmaf(a[r], w0, acc0[r]); acc1[r] = fmaf(a[r], w1, acc1[r]); }
  }
  #pragma unroll
  for (int r=0;r<8;r++){
    int bt = bt0+r;
    xsr[bt*ED_ + c0] = acc0[r];
    zg [bt*ED_ + c0] = acc1[r];
  }
}

// K4b: conv(k=4)+bias+SiLU from xsr (LDS), then [delta_pre | B | C] = xs @ WcT.
// Weight reads COALESCED (WcT[k][c], c=tid).
__global__ __launch_bounds__(384) void k4b_xproj(const float* xsr, const float* convW, const float* convb,
                                                 const float* WcT, const float* dtb,
                                                 float* dxp, float* bcf){
  __shared__ float at[256][8];
  int bt0 = blockIdx.x*8; int tid = threadIdx.x;
  for (int i=tid;i<2048;i+=384){
    int r=i>>8,k=i&255; int bt=bt0+r; int t = bt & (T_SEQ-1);
    float4 wv = *(const float4*)(convW + k*4);
    float s = convb[k];
    if (t>=3) s += xsr[(bt-3)*ED_+k]*wv.x;
    if (t>=2) s += xsr[(bt-2)*ED_+k]*wv.y;
    if (t>=1) s += xsr[(bt-1)*ED_+k]*wv.z;
    s += xsr[bt*ED_+k]*wv.w;
    at[k][r] = s * sigmoidf_(s);
  }
  __syncthreads();
  float acc[8];
  #pragma unroll
  for (int r=0;r<8;r++) acc[r]=0.f;
  int c = tid;
  for (int k=0;k<256;k++){
    float w = WcT[k*384 + c];            // coalesced
    float a[8];
    *(float4*)&a[0] = *(const float4*)&at[k][0];   // broadcast
    *(float4*)&a[4] = *(const float4*)&at[k][4];
    #pragma unroll
    for (int r=0;r<8;r++) acc[r] = fmaf(a[r], w, acc[r]);
  }
  int b4 = bt0 >> 10, tb = bt0 & (T_SEQ-1);
  if (c < 256){
    float bcv = dtb[c];
    float2* pout = (float2*)dxp + (size_t)(b4*ED_ + c)*T_SEQ + tb;
    #pragma unroll
    for (int r=0;r<8;r++){
      float xv = acc[r] + bcv;
      float dv = (xv > 20.f) ? xv : log1pf(__expf(xv));
      pout[r] = make_float2(dv, dv * at[c][r]);   // {delta, delta*xs}
    }
  } else if (c < 320){
    #pragma unroll
    for (int r=0;r<8;r++) bcf[((size_t)(bt0+r)*NS + (c-256))*2 + 0] = acc[r];
  } else {
    #pragma unroll
    for (int r=0;r<8;r++) bcf[((size_t)(bt0+r)*NS + (c-320))*2 + 1] = acc[r];
  }
}

// K5: chunked scan, bc-AMORTIZED. R12 PMC showed: VALUBusy 40% (issue ~25us),
// stall ~37us == 918MB of redundant per-e B/C streaming / 34.5 TB/s L2 BW.
// Fix: block = (b, 4 consecutive e's), 8 waves (512 thr). Wave pair (2w,2w+1)
// both scan chunk w (identical bc addresses -> L1 dedup); each wave covers
// 2 e's, so ONE bc float2 load feeds 2 e's in-register. L2 bc traffic /2../4.
// Grid 256 scan blocks (1/CU) + 16 WoT-transpose blocks. launch_bounds(512,2)
// -> VGPR cap 256 (no R2-style prefetch collapse possible).
// Phase2 reduce: per-wave LDS tile [16t][2e][66] (2-way-free write banks);
// lane L: ri=L&31 (eh=ri>>4, tr=ri&15), hs=L>>5 sums half a row (16 b64 reads
// + 15 adds), shfl_xor(32) combine, lanes 0-31 store two 64B y-segments.
__global__ __launch_bounds__(512,2) void k5_scan(const float* dxpf, const float* bcf,
                                                  const float* Alog, float* yrT,
                                                  const float* outW, float* wot){
  if (blockIdx.x >= 256){
    int bb2 = blockIdx.x - 256;           // 0..15
    int k  = bb2*16 + (threadIdx.x>>5);   // 0..255
    int d  = (threadIdx.x&31)*4;          // 0..124
    float4 v;
    v.x = outW[(d+0)*256 + k];
    v.y = outW[(d+1)*256 + k];
    v.z = outW[(d+2)*256 + k];
    v.w = outW[(d+3)*256 + k];
    *(float4*)&wot[k*128 + d] = v;
    return;
  }
  __shared__ float lcar[3][4][64], lapr[3][4][64];
  __shared__ float red[8][16][2][66];
  int i  = blockIdx.x;
  int tid = threadIdx.x;
  int wv = tid >> 6;             // wave 0..7
  int n  = tid & 63;             // state index (lane)
  int w  = wv >> 1;              // chunk 0..3
  int half = wv & 1;             // e-pair within group
  int x = i & 7;                 // XCD
  int r = i >> 3;                // 0..31
  int b = r & 3;
  int g = r >> 2;                // 0..7
  int eA = x*32 + g*4 + half*2;
  int eB = eA + 1;
  const int CH = T_SEQ/4;        // 256
  int t0 = w*CH;
  float A2A = -__expf(Alog[eA*NS+n]) * LOG2E;
  float A2B = -__expf(Alog[eB*NS+n]) * LOG2E;
  const float2* pdA = (const float2*)dxpf + (size_t)(b*ED_ + eA)*T_SEQ + t0;  // lane=t
  const float2* pdB = (const float2*)dxpf + (size_t)(b*ED_ + eB)*T_SEQ + t0;
  const float2* pbc = (const float2*)bcf  + (size_t)(b*T_SEQ + t0)*NS + n;    // lane=n
  float* pyA = yrT + (size_t)(b*ED_ + eA)*T_SEQ + t0;
  float* pyB = yrT + (size_t)(b*ED_ + eB)*T_SEQ + t0;
  int el = half*2;

  // ---- phase 1: carry-only scan (waves 0..5 = chunks 0..2, pair-split e's)
  if (wv < 6){
    float hA=0.f, hB=0.f, SsA=0.f, SsB=0.f;
    float2 dxcA = pdA[n], dxcB = pdB[n];
    for (int sb=0; sb<CH; sb+=64){
      float2 dxnA = dxcA, dxnB = dxcB;
      if (sb+64 < CH){ dxnA = pdA[sb+64+n]; dxnB = pdB[sb+64+n]; }
      float svA = dxcA.x; DPP6(svA); SsA += rlane_(svA, 63);
      float svB = dxcB.x; DPP6(svB); SsB += rlane_(svB, 63);
      float bA[8], bBv[8];
      #pragma unroll
      for (int j=0;j<8;j++) bA[j] = pbc[(sb+j)*NS].x;
      #pragma unroll
      for (int bb=0; bb<64; bb+=16){
        #pragma unroll
        for (int j=0;j<8;j++) bBv[j] = pbc[(sb+bb+8+j)*NS].x;
        #pragma unroll
        for (int j=0;j<8;j++){
          float sdA = rlane_(dxcA.x, bb+j), suA = rlane_(dxcA.y, bb+j);
          hA = fmaf(exp2_(sdA*A2A), hA, suA*bA[j]);
          float sdB = rlane_(dxcB.x, bb+j), suB = rlane_(dxcB.y, bb+j);
          hB = fmaf(exp2_(sdB*A2B), hB, suB*bA[j]);
        }
        if (bb+16 < 64){
          #pragma unroll
          for (int j=0;j<8;j++) bA[j] = pbc[(sb+bb+16+j)*NS].x;
        }
        #pragma unroll
        for (int j=0;j<8;j++){
          float sdA = rlane_(dxcA.x, bb+8+j), suA = rlane_(dxcA.y, bb+8+j);
          hA = fmaf(exp2_(sdA*A2A), hA, suA*bBv[j]);
          float sdB = rlane_(dxcB.x, bb+8+j), suB = rlane_(dxcB.y, bb+8+j);
          hB = fmaf(exp2_(sdB*A2B), hB, suB*bBv[j]);
        }
      }
      dxcA = dxnA; dxcB = dxnB;
    }
    lcar[w][el  ][n] = hA;  lapr[w][el  ][n] = exp2_(A2A*SsA);
    lcar[w][el+1][n] = hB;  lapr[w][el+1][n] = exp2_(A2B*SsB);
  }
  __syncthreads();

  // ---- combine: h_in for this wave's chunk (both e's)
  float hA = 0.f, hB = 0.f;
  #pragma unroll
  for (int q=0;q<3;q++) if (w > q){
    hA = fmaf(lapr[q][el  ][n], hA, lcar[q][el  ][n]);
    hB = fmaf(lapr[q][el+1][n], hB, lcar[q][el+1][n]);
  }

  // ---- phase 2: full output scan, shared bc load feeds both e's
  {
    float2 dxcA = pdA[n], dxcB = pdB[n];
    int ri = n & 31, hs = n >> 5;
    int eh = ri >> 4, tr = ri & 15;
    const float2* rp = (const float2*)&red[wv][tr][eh][hs*32];
    float* pyE = eh ? pyB : pyA;
    for (int sb=0; sb<CH; sb+=64){
      float2 dxnA = dxcA, dxnB = dxcB;
      if (sb+64 < CH){ dxnA = pdA[sb+64+n]; dxnB = pdB[sb+64+n]; }
      float2 cA[8], cB[8];
      #pragma unroll
      for (int j=0;j<8;j++) cA[j] = pbc[(sb+j)*NS];
      #pragma unroll
      for (int bb=0; bb<64; bb+=16){
        #pragma unroll
        for (int j=0;j<8;j++) cB[j] = pbc[(sb+bb+8+j)*NS];
        #pragma unroll
        for (int j=0;j<8;j++){
          float sdA = rlane_(dxcA.x, bb+j), suA = rlane_(dxcA.y, bb+j);
          hA = fmaf(exp2_(sdA*A2A), hA, suA*cA[j].x);
          red[wv][j][0][n] = hA*cA[j].y;
          float sdB = rlane_(dxcB.x, bb+j), suB = rlane_(dxcB.y, bb+j);
          hB = fmaf(exp2_(sdB*A2B), hB, suB*cA[j].x);
          red[wv][j][1][n] = hB*cA[j].y;
        }
        if (bb+16 < 64){
          #pragma unroll
          for (int j=0;j<8;j++) cA[j] = pbc[(sb+bb+16+j)*NS];
        }
        #pragma unroll
        for (int j=0;j<8;j++){
          float sdA = rlane_(dxcA.x, bb+8+j), suA = rlane_(dxcA.y, bb+8+j);
          hA = fmaf(exp2_(sdA*A2A), hA, suA*cB[j].x);
          red[wv][8+j][0][n] = hA*cB[j].y;
          float sdB = rlane_(dxcB.x, bb+8+j), suB = rlane_(dxcB.y, bb+8+j);
          hB = fmaf(exp2_(sdB*A2B), hB, suB*cB[j].x);
          red[wv][8+j][1][n] = hB*cB[j].y;
        }
        // transpose-reduce the 16t x 2e tile (same-wave DS ops are in-order)
        float s = 0.f;
        #pragma unroll
        for (int jj=0;jj<16;jj++){ float2 v = rp[jj]; s += v.x + v.y; }
        s += __shfl_xor(s, 32);
        if (n < 32) pyE[sb + bb + tr] = s;
      }
      dxcA = dxnA; dxcB = dxnB;
    }
  }
}

// K6: stage yrT (e-major) + xs = u/delta from dxpT via LDS; combine with gate;
// then out = LayerNorm(y @ out_proj_W.T + 2*z)*ln_w + ln_b. WoT reads coalesced.
__global__ __launch_bounds__(256) void k6_out(const float* yrT, const float* dxpf, const float* zg,
                                               const float* Dp, const float* wot, const float* z,
                                               const float* lnw, const float* lnb, float* out){
  __shared__ float yt[256][8];
  __shared__ float xst[256][8];
  __shared__ float psum[4][4], psq[4][4];
  int bt0 = blockIdx.x*8; int tid = threadIdx.x;
  int b4 = bt0 >> 10, tb = bt0 & (T_SEQ-1);
  int el = tid>>3, tl = tid&7;
  #pragma unroll
  for (int gg=0; gg<8; gg++){
    int ee = el + gg*32;
    size_t base = (size_t)(b4*ED_ + ee)*T_SEQ + tb + tl;
    float2 du = ((const float2*)dxpf)[base];
    yt[ee][tl]  = yrT[base];
    xst[ee][tl] = du.y / du.x;        // xs = (delta*xs)/delta; delta >= softplus(-4) ~ 0.018
  }
  __syncthreads();
  for (int i=tid;i<2048;i+=256){
    int rr=i>>8, k=i&255; int bt=bt0+rr;
    float zgv = zg[bt*ED_ + k];
    float yv  = yt[k][rr] + Dp[k]*xst[k][rr];
    yt[k][rr] = yv * zgv * sigmoidf_(zgv);
  }
  __syncthreads();
  int d = tid & 127, gdx = tid>>7;
  float acc[4] = {0.f,0.f,0.f,0.f};
  for (int k=0;k<256;k+=4){
    float w0 = wot[(k+0)*128 + d];       // coalesced
    float w1 = wot[(k+1)*128 + d];
    float w2 = wot[(k+2)*128 + d];
    float w3 = wot[(k+3)*128 + d];
    float4 q0 = *(const float4*)&yt[k+0][gdx*4];   // broadcast
    float4 q1 = *(const float4*)&yt[k+1][gdx*4];
    float4 q2 = *(const float4*)&yt[k+2][gdx*4];
    float4 q3 = *(const float4*)&yt[k+3][gdx*4];
    acc[0] = fmaf(q0.x,w0,acc[0]); acc[1] = fmaf(q0.y,w0,acc[1]);
    acc[2] = fmaf(q0.z,w0,acc[2]); acc[3] = fmaf(q0.w,w0,acc[3]);
    acc[0] = fmaf(q1.x,w1,acc[0]); acc[1] = fmaf(q1.y,w1,acc[1]);
    acc[2] = fmaf(q1.z,w1,acc[2]); acc[3] = fmaf(q1.w,w1,acc[3]);
    acc[0] = fmaf(q2.x,w2,acc[0]); acc[1] = fmaf(q2.y,w2,acc[1]);
    acc[2] = fmaf(q2.z,w2,acc[2]); acc[3] = fmaf(q2.w,w2,acc[3]);
    acc[0] = fmaf(q3.x,w3,acc[0]); acc[1] = fmaf(q3.y,w3,acc[1]);
    acc[2] = fmaf(q3.z,w3,acc[2]); acc[3] = fmaf(q3.w,w3,acc[3]);
  }
  float val[4];
  #pragma unroll
  for (int j=0;j<4;j++){
    int bt = bt0 + gdx*4 + j;
    val[j] = acc[j] + 2.f*z[bt*DM + d];
  }
  int w_id = tid>>6;
  #pragma unroll
  for (int j=0;j<4;j++){
    float s = val[j], q = val[j]*val[j];
    #pragma unroll
    for (int off=32; off>=1; off>>=1){ s += __shfl_down(s, off); q += __shfl_down(q, off); }
    if ((tid&63)==0){ psum[w_id][j]=s; psq[w_id][j]=q; }
  }
  __syncthreads();
  float lw = lnw[d], lb = lnb[d];
  #pragma unroll
  for (int j=0;j<4;j++){
    int bt = bt0 + gdx*4 + j;
    float sum = psum[gdx*2][j] + psum[gdx*2+1][j];
    float sq  = psq [gdx*2][j] + psq [gdx*2+1][j];
    float mu  = sum*(1.f/DM);
    float var = sq*(1.f/DM) - mu*mu;
    float inv = rsqrtf(var + 1e-5f);
    out[bt*DM + d] = (val[j]-mu)*inv*lw + lb;
  }
}

extern "C" void kernel_launch(void* const* d_in, const int* in_sizes, int n_in,
                              void* d_out, int out_size, void* d_ws, size_t ws_size,
                              hipStream_t stream){
  const float* zseq = (const float*)d_in[0];
  const float* aux  = (const float*)d_in[1];
  const float* auxW = (const float*)d_in[2];
  const float* auxb = (const float*)d_in[3];
  const float* lnw  = (const float*)d_in[4];
  const float* lnb  = (const float*)d_in[5];
  const float* rmsw = (const float*)d_in[6];
  const float* inW  = (const float*)d_in[7];
  const float* convW= (const float*)d_in[8];
  const float* convb= (const float*)d_in[9];
  const float* xpW  = (const float*)d_in[10];
  const float* dtW  = (const float*)d_in[11];
  const float* dtb  = (const float*)d_in[12];
  const float* Alog = (const float*)d_in[13];
  const float* Dp   = (const float*)d_in[14];
  const float* outW = (const float*)d_in[15];
  float* out = (float*)d_out;
  float* ws = (float*)d_ws;

  float* z   = ws+OFF_Z;
  float* zg  = ws+OFF_ZG;
  float* xsr = ws+OFF_XSR;
  float* wot = ws+OFF_XSR;   // WoT hosted in XSR head; xsr dead after k4b
  float* WcT = ws+OFF_WC;
  float* yr  = ws+OFF_YR;
  float* wti = ws+OFF_YR;    // WTi hosted in YR head; dead before k5 writes yr
  float* dxp = ws+OFF_DPX;
  float* bcp = ws+OFF_BC;

  k0_t     <<<128,256,0,stream>>>(inW, wti);
  k2_fused <<<896,256,0,stream>>>(zseq,aux,auxW,auxb,rmsw,wti,xpW,dtW,z,xsr,zg,WcT);
  k4b_xproj<<<512,384,0,stream>>>(xsr,convW,convb,WcT,dtb,dxp,bcp);
  k5_scan  <<<272,512,0,stream>>>(dxp,bcp,Alog,yr,outW,wot);
  k6_out   <<<512,256,0,stream>>>(yr,dxp,zg,Dp,wot,z,lnw,lnb,out);
}